// Round 2
// baseline (2035.472 us; speedup 1.0000x reference)
//
#include <hip/hip_runtime.h>

#define DEV static __device__ __forceinline__

constexpr int BATCH = 256;

DEV float leakyf(float x){ return x > 0.f ? x : 0.2f * x; }

// ---------------- weight transpose: w[OC][RED] -> wT[RED][OC] ----------------
__global__ __launch_bounds__(256) void kwT(const float* __restrict__ w,
                                           float* __restrict__ wt, int OC, int RED){
  int i = blockIdx.x * 256 + threadIdx.x;
  if (i >= OC * RED) return;
  int oc = i / RED, r = i % RED;
  wt[r * OC + oc] = w[i];
}

// ---------------- direct conv: one thread = one (n,oh,ow), OCG channels -----
// ACT: 0 = bias+leaky, 1 = bias + BN(eval) + relu
template<int IC,int OC,int OCG,int K,int S,int P,int IH,int IW,int OH,int OW,int ACT>
__global__ __launch_bounds__(256) void conv_k(
    const float* __restrict__ x, const float* __restrict__ wT,
    const float* __restrict__ bias,
    const float* __restrict__ bng, const float* __restrict__ bnb,
    const float* __restrict__ bnm, const float* __restrict__ bnv,
    float* __restrict__ out){
  constexpr int PIX = OH * OW;
  int idx = blockIdx.x * 256 + threadIdx.x;
  if (idx >= BATCH * PIX) return;
  int n = idx / PIX, p = idx % PIX;
  int oh = p / OW, ow = p % OW;
  int ocb = blockIdx.y * OCG;

  float acc[OCG];
  #pragma unroll
  for (int j = 0; j < OCG; ++j) acc[j] = 0.f;

  const float* xin = x + (size_t)n * IC * IH * IW;
  for (int ic = 0; ic < IC; ++ic){
    const float* xc = xin + (size_t)ic * IH * IW;
    #pragma unroll
    for (int kh = 0; kh < K; ++kh){
      int ih = oh * S - P + kh;
      bool rv = (ih >= 0) && (ih < IH);
      const float* xr = xc + (size_t)ih * IW;
      #pragma unroll
      for (int kw = 0; kw < K; ++kw){
        int iw = ow * S - P + kw;
        float v = (rv && iw >= 0 && iw < IW) ? xr[iw] : 0.f;
        const float* wrow = wT + (size_t)((ic * K + kh) * K + kw) * OC + ocb;
        #pragma unroll
        for (int j = 0; j < OCG; ++j) acc[j] += v * wrow[j];
      }
    }
  }

  #pragma unroll
  for (int j = 0; j < OCG; ++j){
    int oc = ocb + j;
    float val = acc[j] + bias[oc];
    if (ACT == 1){
      float scale = bng[oc] / sqrtf(bnv[oc] + 1e-5f);
      val = (val - bnm[oc]) * scale + bnb[oc];
      val = fmaxf(val, 0.f);
    } else {
      val = leakyf(val);
    }
    out[((size_t)(n * OC + oc) * OH + oh) * OW + ow] = val;
  }
}

// ---------------- 2x2 stride-1 maxpool ----------------
template<int C,int IH,int IW>
__global__ __launch_bounds__(256) void pool_k(const float* __restrict__ in,
                                              float* __restrict__ out){
  constexpr int OH = IH - 1, OW = IW - 1;
  int idx = blockIdx.x * 256 + threadIdx.x;
  if (idx >= BATCH * C * OH * OW) return;
  int ow = idx % OW; int t = idx / OW;
  int oh = t % OH;   t /= OH;          // t = n*C + c
  const float* p = in + ((size_t)t * IH + oh) * IW + ow;
  out[idx] = fmaxf(fmaxf(p[0], p[1]), fmaxf(p[IW], p[IW + 1]));
}

// ---------------- scout gate: spatial mean -> logits -> softmax -> top2 -----
__global__ __launch_bounds__(256) void gate_k(const float* __restrict__ s2,
                                              const float* __restrict__ cw,
                                              const float* __restrict__ cb,
                                              float* __restrict__ comb){
  int n = blockIdx.x;
  int tid = threadIdx.x;
  int c = tid >> 3;     // 0..31
  int sub = tid & 7;    // 0..7
  const float* p = s2 + ((size_t)n * 32 + c) * 784;
  float s = 0.f;
  for (int i = sub * 98; i < sub * 98 + 98; ++i) s += p[i];
  __shared__ float red[32][8];
  red[c][sub] = s;
  __syncthreads();
  if (tid < 32){
    float tot = 0.f;
    #pragma unroll
    for (int k = 0; k < 8; ++k) tot += red[tid][k];
    red[tid][0] = tot / 784.f;
  }
  __syncthreads();
  if (tid == 0){
    float lg[3];
    for (int e = 0; e < 3; ++e){
      float a = cb[e];
      for (int c2 = 0; c2 < 32; ++c2) a += red[c2][0] * cw[e * 32 + c2];
      lg[e] = a;
    }
    float m = fmaxf(lg[0], fmaxf(lg[1], lg[2]));
    float ex[3], sum = 0.f;
    for (int e = 0; e < 3; ++e){ ex[e] = expf(lg[e] - m); sum += ex[e]; }
    float pr[3];
    for (int e = 0; e < 3; ++e) pr[e] = ex[e] / sum;
    int i1 = 0;
    if (pr[1] > pr[0]) i1 = 1;
    if (pr[2] > pr[i1]) i1 = 2;
    int i2 = -1;
    for (int e = 0; e < 3; ++e){
      if (e == i1) continue;
      if (i2 < 0 || pr[e] > pr[i2]) i2 = e;
    }
    float s12 = pr[i1] + pr[i2] + 1e-6f;
    float cmb[3] = {0.f, 0.f, 0.f};
    cmb[i1] = pr[i1] / s12;
    cmb[i2] = pr[i2] / s12;
    comb[n * 3 + 0] = cmb[0];
    comb[n * 3 + 1] = cmb[1];
    comb[n * 3 + 2] = cmb[2];
  }
}

// ------ fused maxpool2s1(27->26) + adaptive avg pool(26->3), write flat -----
__global__ __launch_bounds__(256) void papool_k(const float* __restrict__ in,
                                                float* __restrict__ flat){
  // in: conv4 output [B,128,27,27]
  int idx = blockIdx.x * 256 + threadIdx.x;
  if (idx >= BATCH * 128 * 9) return;
  int j = idx % 3; int t = idx / 3;
  int i = t % 3;   t /= 3;
  int c = t % 128; int n = t / 128;
  int hs = (i * 26) / 3, he = ((i + 1) * 26 + 2) / 3;   // pooled-image rows
  int ws = (j * 26) / 3, we = ((j + 1) * 26 + 2) / 3;   // pooled-image cols
  const float* p = in + ((size_t)n * 128 + c) * 729;
  float s = 0.f;
  for (int r = hs; r < he; ++r){
    const float* r0 = p + r * 27;
    const float* r1 = r0 + 27;
    for (int cc = ws; cc < we; ++cc){
      float m = fmaxf(fmaxf(r0[cc], r0[cc + 1]), fmaxf(r1[cc], r1[cc + 1]));
      s += m;
    }
  }
  flat[(size_t)n * 1152 + c * 9 + i * 3 + j] = s / (float)((he - hs) * (we - ws));
}

// ---------------- tiled GEMM: out[M,N] = A[M,K] * W[N,K]^T + bias -----------
// grid (N/64, M/64, E). ACT: 0 none, 1 leaky.
template<int ACT>
__global__ __launch_bounds__(256) void gemm_k(const float* __restrict__ A,
                                              const float* __restrict__ W,
                                              const float* __restrict__ bias,
                                              float* __restrict__ out,
                                              int M, int N, int K, long strideA){
  int e = blockIdx.z;
  A += (size_t)e * strideA;
  W += (size_t)e * N * K;
  bias += e * N;
  out += (size_t)e * M * N;

  __shared__ float As[16][68];
  __shared__ float Bs[16][68];
  int tid = threadIdx.x;
  int m0 = blockIdx.y * 64, n0 = blockIdx.x * 64;
  int lr = tid >> 2;          // 0..63
  int lk = (tid & 3) * 4;     // 0,4,8,12
  int tx = tid & 15, ty = tid >> 4;
  float acc[4][4] = {};

  for (int k0 = 0; k0 < K; k0 += 16){
    float4 av = *(const float4*)&A[(size_t)(m0 + lr) * K + k0 + lk];
    float4 bv = *(const float4*)&W[(size_t)(n0 + lr) * K + k0 + lk];
    As[lk + 0][lr] = av.x; As[lk + 1][lr] = av.y;
    As[lk + 2][lr] = av.z; As[lk + 3][lr] = av.w;
    Bs[lk + 0][lr] = bv.x; Bs[lk + 1][lr] = bv.y;
    Bs[lk + 2][lr] = bv.z; Bs[lk + 3][lr] = bv.w;
    __syncthreads();
    #pragma unroll
    for (int k = 0; k < 16; ++k){
      float a[4], b[4];
      #pragma unroll
      for (int i = 0; i < 4; ++i) a[i] = As[k][ty * 4 + i];
      #pragma unroll
      for (int j = 0; j < 4; ++j) b[j] = Bs[k][tx * 4 + j];
      #pragma unroll
      for (int i = 0; i < 4; ++i)
        #pragma unroll
        for (int j = 0; j < 4; ++j) acc[i][j] += a[i] * b[j];
    }
    __syncthreads();
  }

  #pragma unroll
  for (int i = 0; i < 4; ++i){
    int m = m0 + ty * 4 + i;
    #pragma unroll
    for (int j = 0; j < 4; ++j){
      int nn = n0 + tx * 4 + j;
      float v = acc[i][j] + bias[nn];
      if (ACT == 1) v = leakyf(v);
      out[(size_t)m * N + nn] = v;
    }
  }
}

// ---------------- final gated combine ----------------
__global__ __launch_bounds__(256) void comb_k(const float* __restrict__ h3,
                                              const float* __restrict__ comb,
                                              float* __restrict__ out){
  int idx = blockIdx.x * 256 + threadIdx.x;
  if (idx >= BATCH * 512) return;
  int o = idx % 512, b = idx / 512;
  float s = 0.f;
  #pragma unroll
  for (int e = 0; e < 3; ++e)
    s += comb[b * 3 + e] * h3[((size_t)e * BATCH + b) * 512 + o];
  out[idx] = s;
}

// ============================================================================
extern "C" void kernel_launch(void* const* d_in, const int* in_sizes, int n_in,
                              void* d_out, int out_size, void* d_ws, size_t ws_size,
                              hipStream_t stream){
  const float* x    = (const float*)d_in[0];
  const float* tw1  = (const float*)d_in[1];  const float* tb1 = (const float*)d_in[2];
  const float* tw2  = (const float*)d_in[3];  const float* tb2 = (const float*)d_in[4];
  const float* tw3  = (const float*)d_in[5];  const float* tb3 = (const float*)d_in[6];
  const float* tw4  = (const float*)d_in[7];  const float* tb4 = (const float*)d_in[8];
  const float* sw1  = (const float*)d_in[9];  const float* sb1 = (const float*)d_in[10];
  const float* bn1g = (const float*)d_in[11]; const float* bn1b = (const float*)d_in[12];
  const float* bn1m = (const float*)d_in[13]; const float* bn1v = (const float*)d_in[14];
  const float* sw2  = (const float*)d_in[15]; const float* sb2 = (const float*)d_in[16];
  const float* bn2g = (const float*)d_in[17]; const float* bn2b = (const float*)d_in[18];
  const float* bn2m = (const float*)d_in[19]; const float* bn2v = (const float*)d_in[20];
  const float* cw   = (const float*)d_in[21]; const float* cb  = (const float*)d_in[22];
  const float* ew1  = (const float*)d_in[23]; const float* eb1 = (const float*)d_in[24];
  const float* ew2  = (const float*)d_in[25]; const float* eb2 = (const float*)d_in[26];
  const float* ew3  = (const float*)d_in[27]; const float* eb3 = (const float*)d_in[28];
  float* out = (float*)d_out;

  // ---- workspace layout (floats) — total ~38.6M floats ≈ 154 MB ----
  float* ws = (float*)d_ws;
  size_t off = 0;
  float* comb  = ws + off; off += 768;
  float* tw1T  = ws + off; off += 16 * 27;
  float* tw2T  = ws + off; off += 32 * 400;
  float* tw3T  = ws + off; off += 64 * 288;
  float* tw4T  = ws + off; off += 128 * 576;
  float* sw1T  = ws + off; off += 16 * 147;
  float* sw2T  = ws + off; off += 32 * 144;
  float* flat  = ws + off; off += (size_t)BATCH * 1152;          // 294,912
  float* h1    = ws + off; off += (size_t)BATCH * 3 * 1024;      // 786,432
  float* h2    = ws + off; off += (size_t)BATCH * 3 * 512;       // 393,216
  float* h3    = ws + off; off += (size_t)BATCH * 3 * 512;       // 393,216
  float* bufA  = ws + off; off += (size_t)BATCH * 16 * 56 * 56;  // 12,845,056
  float* bufB  = ws + off; off += (size_t)BATCH * 128 * 27 * 27; // 23,887,872
  (void)ws_size; (void)in_sizes; (void)n_in; (void)out_size;

  dim3 blk(256);

  // ---- transpose all conv weights to [red][OC] ----
  kwT<<<dim3(( 16*27 +255)/256), blk, 0, stream>>>(tw1, tw1T, 16, 27);
  kwT<<<dim3(( 32*400+255)/256), blk, 0, stream>>>(tw2, tw2T, 32, 400);
  kwT<<<dim3(( 64*288+255)/256), blk, 0, stream>>>(tw3, tw3T, 64, 288);
  kwT<<<dim3((128*576+255)/256), blk, 0, stream>>>(tw4, tw4T, 128, 576);
  kwT<<<dim3(( 16*147+255)/256), blk, 0, stream>>>(sw1, sw1T, 16, 147);
  kwT<<<dim3(( 32*144+255)/256), blk, 0, stream>>>(sw2, sw2T, 32, 144);

  // ---- scout router ----
  conv_k<3,16,16,7,4,3,224,224,56,56,1><<<dim3(3136,1), blk, 0, stream>>>(
      x, sw1T, sb1, bn1g, bn1b, bn1m, bn1v, bufA);
  conv_k<16,32,32,3,2,1,56,56,28,28,1><<<dim3(784,1), blk, 0, stream>>>(
      bufA, sw2T, sb2, bn2g, bn2b, bn2m, bn2v, bufB);
  gate_k<<<dim3(256), blk, 0, stream>>>(bufB, cw, cb, comb);

  // ---- trunk ----
  conv_k<3,16,16,3,4,1,224,224,56,56,0><<<dim3(3136,1), blk, 0, stream>>>(
      x, tw1T, tb1, nullptr, nullptr, nullptr, nullptr, bufA);
  pool_k<16,56,56><<<dim3(48400), blk, 0, stream>>>(bufA, bufB);     // ->[B,16,55,55]
  conv_k<16,32,32,5,2,2,55,55,28,28,0><<<dim3(784,1), blk, 0, stream>>>(
      bufB, tw2T, tb2, nullptr, nullptr, nullptr, nullptr, bufA);
  pool_k<32,28,28><<<dim3(23328), blk, 0, stream>>>(bufA, bufB);     // ->[B,32,27,27]
  conv_k<32,64,32,3,1,1,27,27,27,27,0><<<dim3(729,2), blk, 0, stream>>>(
      bufB, tw3T, tb3, nullptr, nullptr, nullptr, nullptr, bufA);
  conv_k<64,128,32,3,1,1,27,27,27,27,0><<<dim3(729,4), blk, 0, stream>>>(
      bufA, tw4T, tb4, nullptr, nullptr, nullptr, nullptr, bufB);
  papool_k<<<dim3(1152), blk, 0, stream>>>(bufB, flat);              // fused pool+apool

  // ---- MoE head (dense over 3 experts) ----
  gemm_k<1><<<dim3(16,4,3), blk, 0, stream>>>(flat, ew1, eb1, h1, 256, 1024, 1152, 0L);
  gemm_k<1><<<dim3( 8,4,3), blk, 0, stream>>>(h1,   ew2, eb2, h2, 256,  512, 1024, 256L*1024);
  gemm_k<0><<<dim3( 8,4,3), blk, 0, stream>>>(h2,   ew3, eb3, h3, 256,  512,  512, 256L*512);
  comb_k<<<dim3(512), blk, 0, stream>>>(h3, comb, out);
}